// Round 5
// baseline (1298.723 us; speedup 1.0000x reference)
//
#include <hip/hip_runtime.h>
#include <hip/hip_bf16.h>
#include <math.h>

#define B_ 64
#define C_ 512
#define N_ 1024
#define D_ 128
#define K_ 8

typedef __attribute__((ext_vector_type(8))) short bf16x8;  // 8 bf16 = 4 VGPRs
typedef __attribute__((ext_vector_type(4))) float f32x4;
typedef unsigned short ushort_t;

__device__ __forceinline__ unsigned short f2bs(float f) {
    union { __hip_bfloat16 h; unsigned short s; } u;
    u.h = __float2bfloat16(f);
    return u.s;
}
__device__ __forceinline__ float bs2f(unsigned short s) {
    union { unsigned int u; float f; } v;
    v.u = ((unsigned int)s) << 16;
    return v.f;
}
__device__ __forceinline__ float sigmoidf_(float x) { return 1.0f / (1.0f + expf(-x)); }
__device__ __forceinline__ float gelu_exact(float x) {
    return 0.5f * x * (1.0f + erff(x * 0.7071067811865476f));
}

// ---------------------------------------------------------------------------
// K0: weight prep (proven) + zeroing of the group-barrier counters.
// ---------------------------------------------------------------------------
__global__ __launch_bounds__(256) void prep_weights(
    const float* __restrict__ Wp, const float* __restrict__ Wk,
    const float* __restrict__ Wv, const float* __restrict__ W_ih,
    const float* __restrict__ W_hh,
    ushort_t* __restrict__ WpT, ushort_t* __restrict__ WkT,
    ushort_t* __restrict__ WvT, float* __restrict__ WTih,
    float* __restrict__ WThh, unsigned* __restrict__ bar)
{
    int tid = blockIdx.x * 256 + threadIdx.x;   // grid 256*256 = 65536
    {
        int c = tid >> 7, d = tid & 127;        // coalesced read of Wp
        WpT[d * 512 + c] = f2bs(Wp[tid]);
    }
    if (tid < 16384) {
        int c = tid >> 7, d = tid & 127;
        WkT[d * 128 + c] = f2bs(Wk[tid]);
        WvT[d * 128 + c] = f2bs(Wv[tid]);
    }
    if (tid < 49152) {
        int j = tid >> 7, c = tid & 127;        // coalesced read of W_ih
        WTih[c * 384 + j] = W_ih[tid];
        WThh[c * 384 + j] = W_hh[tid];
    }
    if (tid < 64) bar[tid] = 0u;                // barrier counters (re-poison-safe)
}

// ---------------------------------------------------------------------------
// K1: inputs = LN(x_flat @ Wp + bp)*g+b via MFMA bf16 (unchanged, proven).
// ---------------------------------------------------------------------------
__global__ __launch_bounds__(256) void proj_ln_mfma(
    const float* __restrict__ x, const ushort_t* __restrict__ WpT,
    const float* __restrict__ bp, const float* __restrict__ g_in,
    const float* __restrict__ b_in, ushort_t* __restrict__ outb)
{
    __shared__ ushort_t Al[64 * 40];
    __shared__ ushort_t Bl[128 * 40];
    __shared__ float red[64][2][2];
    const int t = threadIdx.x;
    const int b = blockIdx.x >> 4;
    const int n0 = (blockIdx.x & 15) << 6;
    const int w = t >> 6, lane = t & 63;
    const int quad = lane >> 4, m = lane & 15;
    const int rowoff = (w >> 1) << 5;   // 0 / 32
    const int coloff = (w & 1) << 6;    // 0 / 64

    f32x4 acc[2][4];
#pragma unroll
    for (int r = 0; r < 2; ++r)
#pragma unroll
        for (int c = 0; c < 4; ++c) acc[r][c] = (f32x4){0.f, 0.f, 0.f, 0.f};

    const float* xb = x + (size_t)b * (C_ * N_);
    for (int c0 = 0; c0 < C_; c0 += 32) {
#pragma unroll
        for (int i = 0; i < 8; ++i) {
            int idx = t + (i << 8);
            int cc = idx >> 6, nn = idx & 63;
            Al[nn * 40 + cc] = f2bs(xb[(size_t)(c0 + cc) * N_ + n0 + nn]);
        }
#pragma unroll
        for (int i = 0; i < 2; ++i) {
            int idx = t + (i << 8);           // 0..511
            int d = idx >> 2, seg = idx & 3;  // 128 rows x 4 segs of 8
            *(bf16x8*)&Bl[d * 40 + seg * 8] =
                *(const bf16x8*)&WpT[d * 512 + c0 + seg * 8];
        }
        __syncthreads();
        bf16x8 af[2], bfr[4];
#pragma unroll
        for (int r = 0; r < 2; ++r)
            af[r] = *(const bf16x8*)&Al[(rowoff + 16 * r + m) * 40 + quad * 8];
#pragma unroll
        for (int c = 0; c < 4; ++c)
            bfr[c] = *(const bf16x8*)&Bl[(coloff + 16 * c + m) * 40 + quad * 8];
#pragma unroll
        for (int r = 0; r < 2; ++r)
#pragma unroll
            for (int c = 0; c < 4; ++c)
                acc[r][c] = __builtin_amdgcn_mfma_f32_16x16x32_bf16(af[r], bfr[c], acc[r][c], 0, 0, 0);
        __syncthreads();
    }
    float gv[4], bv[4], bpv[4];
#pragma unroll
    for (int c = 0; c < 4; ++c) {
        int col = coloff + 16 * c + m;
        bpv[c] = bp[col]; gv[c] = g_in[col]; bv[c] = b_in[col];
    }
#pragma unroll
    for (int r = 0; r < 2; ++r)
#pragma unroll
        for (int c = 0; c < 4; ++c)
#pragma unroll
            for (int g = 0; g < 4; ++g) acc[r][c][g] += bpv[c];

#pragma unroll
    for (int r = 0; r < 2; ++r) {
#pragma unroll
        for (int g = 0; g < 4; ++g) {
            float s = 0.f, s2 = 0.f;
#pragma unroll
            for (int c = 0; c < 4; ++c) { float v = acc[r][c][g]; s += v; s2 += v * v; }
#pragma unroll
            for (int off = 1; off < 16; off <<= 1) {
                s += __shfl_xor(s, off, 64);
                s2 += __shfl_xor(s2, off, 64);
            }
            if (m == 0) {
                int row = rowoff + 16 * r + quad * 4 + g;
                red[row][w & 1][0] = s;
                red[row][w & 1][1] = s2;
            }
        }
    }
    __syncthreads();
#pragma unroll
    for (int r = 0; r < 2; ++r) {
#pragma unroll
        for (int g = 0; g < 4; ++g) {
            int row = rowoff + 16 * r + quad * 4 + g;
            float s = red[row][0][0] + red[row][1][0];
            float s2 = red[row][0][1] + red[row][1][1];
            float mean = s * (1.f / 128.f);
            float var = s2 * (1.f / 128.f) - mean * mean;
            float rs = rsqrtf(var + 1e-5f);
            size_t base = ((size_t)b * N_ + n0 + row) * D_;
#pragma unroll
            for (int c = 0; c < 4; ++c) {
                int col = coloff + 16 * c + m;
                float v = (acc[r][c][g] - mean) * rs * gv[c] + bv[c];
                outb[base + col] = f2bs(v);
            }
        }
    }
}

// ---------------------------------------------------------------------------
// K2: k/v = A@Wk/Wv + bias (unchanged, proven).
// ---------------------------------------------------------------------------
__global__ __launch_bounds__(256) void kv_mfma(
    const ushort_t* __restrict__ A,
    const ushort_t* __restrict__ WkT, const float* __restrict__ bk,
    const ushort_t* __restrict__ WvT, const float* __restrict__ bv,
    ushort_t* __restrict__ kout, ushort_t* __restrict__ vout)
{
    __shared__ ushort_t Al[64 * 40];
    __shared__ ushort_t Bk[128 * 40];
    __shared__ ushort_t Bv[128 * 40];
    const int t = threadIdx.x;
    const int row0 = blockIdx.x << 6;
    const int w = t >> 6, lane = t & 63;
    const int quad = lane >> 4, m = lane & 15;
    const int is_v = w >> 1;
    const int rowoff = (w & 1) << 5;

    f32x4 acc[2][8];
#pragma unroll
    for (int r = 0; r < 2; ++r)
#pragma unroll
        for (int c = 0; c < 8; ++c) acc[r][c] = (f32x4){0.f, 0.f, 0.f, 0.f};

    for (int c0 = 0; c0 < D_; c0 += 32) {
#pragma unroll
        for (int i = 0; i < 2; ++i) {
            int idx = t + (i << 8);
            int rr = idx >> 3, cc4 = (idx & 7) << 2;
            *(ushort4*)&Al[rr * 40 + cc4] =
                *(const ushort4*)&A[(size_t)(row0 + rr) * D_ + c0 + cc4];
        }
#pragma unroll
        for (int i = 0; i < 2; ++i) {
            int idx = t + (i << 8);
            int d = idx >> 2, seg = idx & 3;
            *(bf16x8*)&Bk[d * 40 + seg * 8] =
                *(const bf16x8*)&WkT[d * 128 + c0 + seg * 8];
            *(bf16x8*)&Bv[d * 40 + seg * 8] =
                *(const bf16x8*)&WvT[d * 128 + c0 + seg * 8];
        }
        __syncthreads();
        const ushort_t* Bsrc = is_v ? Bv : Bk;
        bf16x8 af[2], bfr[8];
#pragma unroll
        for (int r = 0; r < 2; ++r)
            af[r] = *(const bf16x8*)&Al[(rowoff + 16 * r + m) * 40 + quad * 8];
#pragma unroll
        for (int c = 0; c < 8; ++c)
            bfr[c] = *(const bf16x8*)&Bsrc[(16 * c + m) * 40 + quad * 8];
#pragma unroll
        for (int r = 0; r < 2; ++r)
#pragma unroll
            for (int c = 0; c < 8; ++c)
                acc[r][c] = __builtin_amdgcn_mfma_f32_16x16x32_bf16(af[r], bfr[c], acc[r][c], 0, 0, 0);
        __syncthreads();
    }
    const float* bias = is_v ? bv : bk;
    ushort_t* dst = is_v ? vout : kout;
    float bval[8];
#pragma unroll
    for (int c = 0; c < 8; ++c) bval[c] = bias[16 * c + m];
#pragma unroll
    for (int r = 0; r < 2; ++r) {
#pragma unroll
        for (int g = 0; g < 4; ++g) {
            int row = rowoff + 16 * r + quad * 4 + g;
            size_t base = (size_t)(row0 + row) * D_;
#pragma unroll
            for (int c = 0; c < 8; ++c)
                dst[base + 16 * c + m] = f2bs(acc[r][c][g] + bval[c]);
        }
    }
}

// ---------------------------------------------------------------------------
// K3 v4: fused slot loop, GPU-wide. 256 blocks x 512 threads: 4 blocks per
// batch element b, each owning an N-quarter (qd). Slot-state math (LN, q,
// GRU, MLP) is DUPLICATED in the 4 group blocks (~1.4M MAC, ~1us) so the
// only cross-block dependency is the upd/S reduction: plain global stores of
// per-quarter partials + one device-scope arrival barrier per iteration.
// v3 failure mode (806us): 64 blocks = 64/256 CUs busy, 27 full-drain
// barriers/iter serialized on 2 waves/SIMD. v4: 4x CU spread, ~19 barriers,
// 1/4 chunk work per block.
// Barrier: monotonic counter per b (targets 4/8/12), zeroed by prep_weights
// each launch; per-iter partial buffers -> no WAR across iters; 256 blocks
// at 1 block/CU (LDS 104KB) are all co-resident. Cross-XCD visibility via
// __threadfence() release/acquire around the device-scope atomicAdd.
// ---------------------------------------------------------------------------
__global__ __launch_bounds__(512, 2) void fused_slots(
    const ushort_t* __restrict__ kb, const ushort_t* __restrict__ vb,
    const float* __restrict__ noise, const float* __restrict__ mu,
    const float* __restrict__ lsig,
    const float* __restrict__ g_slots, const float* __restrict__ b_slots,
    const float* __restrict__ Wq, const float* __restrict__ bq,
    const float* __restrict__ WTih, const float* __restrict__ WThh,
    const float* __restrict__ b_ih, const float* __restrict__ b_hh,
    const float* __restrict__ W1, const float* __restrict__ b1,
    const float* __restrict__ W2, const float* __restrict__ b2,
    const float* __restrict__ g_mlp, const float* __restrict__ b_mlp,
    float* __restrict__ upd_part, float* __restrict__ S_part,
    unsigned* __restrict__ bar,
    float* __restrict__ out_slots, float* __restrict__ out_attn)
{
    __shared__ __align__(16) float sl[8][132];      // slots (duplicated state)
    __shared__ __align__(16) float u_[8][132];      // ln -> upd -> ln_mlp temp
    __shared__ __align__(16) float sn_[8][132];     // GRU output
    __shared__ __align__(16) float q_[8][132];
    __shared__ __align__(16) float at8[8][264];     // logits -> attn (quarter)
    __shared__ __align__(16) char scratch[69632];   // kvt[256][136] U red U gates
    __shared__ __align__(16) float hm_[8][260];     // MLP hidden
    __shared__ float red2[4][8];
    __shared__ float S_[8];
    __shared__ float mrs_[8][2];

    ushort_t* kvt = (ushort_t*)scratch;
    float* red = (float*)scratch;
    float* gxb = (float*)scratch;            // [8][384] GRU input-gates
    float* ghb = (float*)scratch + 3072;     // [8][384] GRU hidden-gates

    const int t = threadIdx.x;
    const int b = blockIdx.x >> 2;
    const int qd = blockIdx.x & 3;
    const int nbase = qd << 8;
    const int wv = t >> 6, lane = t & 63;
    const float SCALE = 0.08838834764831845f;

    // slots init (duplicated per group)
    for (int i = t; i < 1024; i += 512)
        sl[i >> 7][i & 127] = mu[i] + expf(lsig[i]) * noise[b * 1024 + i];
    __syncthreads();

    for (int it = 0; it < 3; ++it) {
        const int last = (it == 2);

        // ---- A1: LN stats (wave wv owns slot-row wv)
        {
            float v0 = sl[wv][lane], v1 = sl[wv][lane + 64];
            float s = v0 + v1, s2 = v0 * v0 + v1 * v1;
            for (int off = 32; off > 0; off >>= 1) {
                s += __shfl_down(s, off, 64);
                s2 += __shfl_down(s2, off, 64);
            }
            if (lane == 0) {
                float mean = s * (1.f / 128.f);
                float var = s2 * (1.f / 128.f) - mean * mean;
                mrs_[wv][0] = mean; mrs_[wv][1] = rsqrtf(var + 1e-5f);
            }
        }
        __syncthreads();

        // ---- A2: u_ = LN(slots)*g+b
        for (int i = t; i < 1024; i += 512) {
            int k = i >> 7, d = i & 127;
            u_[k][d] = (sl[k][d] - mrs_[k][0]) * mrs_[k][1] * g_slots[d] + b_slots[d];
        }
        __syncthreads();

        // ---- A3: q = u_ @ Wq + bq (coalesced; one weight load -> 2 slots)
        {
            const int d = t & 127, kk = t >> 7;
            float a0 = bq[d], a1 = bq[d];
            for (int c0 = 0; c0 < 128; c0 += 4) {
                f32x4 u0 = *(const f32x4*)&u_[kk][c0];
                f32x4 u1 = *(const f32x4*)&u_[kk + 4][c0];
#pragma unroll
                for (int e = 0; e < 4; ++e) {
                    float w = Wq[(size_t)(c0 + e) * 128 + d];
                    a0 = fmaf(u0[e], w, a0);
                    a1 = fmaf(u1[e], w, a1);
                }
            }
            q_[kk][d] = a0;
            q_[kk + 4][d] = a1;
        }
        __syncthreads();

        // ---- B: stage k-quarter (256 rows) into LDS, coalesced
#pragma unroll
        for (int i = 0; i < 8; ++i) {
            int idx = t + (i << 9);            // 0..4095
            int rr = idx >> 4, u8 = (idx & 15) << 3;
            *(bf16x8*)&kvt[rr * 136 + u8] =
                *(const bf16x8*)&kb[((size_t)b * N_ + nbase + rr) * D_ + u8];
        }
        __syncthreads();

        // ---- B2: logits. Thread (row = t&255, kq = t>>8) -> 4 k-dots.
        {
            const int row = t & 255, kq = t >> 8;
            float acc[4] = {0.f, 0.f, 0.f, 0.f};
            for (int c0 = 0; c0 < 128; c0 += 8) {
                bf16x8 kr = *(const bf16x8*)&kvt[row * 136 + c0];
                float kf[8];
#pragma unroll
                for (int j = 0; j < 8; ++j) kf[j] = bs2f((ushort_t)kr[j]);
#pragma unroll
                for (int kk = 0; kk < 4; ++kk) {
                    f32x4 qa = *(const f32x4*)&q_[4 * kq + kk][c0];
                    f32x4 qb = *(const f32x4*)&q_[4 * kq + kk][c0 + 4];
                    acc[kk] = fmaf(qa[0], kf[0], acc[kk]);
                    acc[kk] = fmaf(qa[1], kf[1], acc[kk]);
                    acc[kk] = fmaf(qa[2], kf[2], acc[kk]);
                    acc[kk] = fmaf(qa[3], kf[3], acc[kk]);
                    acc[kk] = fmaf(qb[0], kf[4], acc[kk]);
                    acc[kk] = fmaf(qb[1], kf[5], acc[kk]);
                    acc[kk] = fmaf(qb[2], kf[6], acc[kk]);
                    acc[kk] = fmaf(qb[3], kf[7], acc[kk]);
                }
            }
#pragma unroll
            for (int kk = 0; kk < 4; ++kk)
                at8[4 * kq + kk][row] = acc[kk];
        }
        __syncthreads();

        // ---- softmax over k at each local n (t<256) + quarter S partials
        if (t < 256) {
            float l[8];
#pragma unroll
            for (int k = 0; k < 8; ++k) l[k] = at8[k][t] * SCALE;
            float mx = l[0];
#pragma unroll
            for (int k = 1; k < 8; ++k) mx = fmaxf(mx, l[k]);
            float e[8], ssum = 0.f;
#pragma unroll
            for (int k = 0; k < 8; ++k) { e[k] = expf(l[k] - mx); ssum += e[k]; }
            float inv = 1.f / ssum;
            float p[8];
#pragma unroll
            for (int k = 0; k < 8; ++k) {
                p[k] = e[k] * inv;
                at8[k][t] = p[k];
                if (last) out_attn[((size_t)b * K_ + k) * N_ + nbase + t] = p[k];
            }
#pragma unroll
            for (int k = 0; k < 8; ++k) {
                float v = p[k];
                for (int off = 32; off > 0; off >>= 1) v += __shfl_down(v, off, 64);
                if (lane == 0) red2[wv][k] = v;
            }
        }
        __syncthreads();
        if (t < 8) {
            float ss = red2[0][t] + red2[1][t] + red2[2][t] + red2[3][t];
            S_part[((size_t)it * 64 + b) * 32 + qd * 8 + t] = ss;
        }

        // ---- C: stage v-quarter (overwrites kvt; logits done)
        __syncthreads();
#pragma unroll
        for (int i = 0; i < 8; ++i) {
            int idx = t + (i << 9);
            int rr = idx >> 4, u8 = (idx & 15) << 3;
            *(bf16x8*)&kvt[rr * 136 + u8] =
                *(const bf16x8*)&vb[((size_t)b * N_ + nbase + rr) * D_ + u8];
        }
        __syncthreads();

        // ---- C2: upd quarter-partial = attn(quarter) @ v(quarter)
        {
            float acc[8][4];
#pragma unroll
            for (int k = 0; k < 8; ++k)
#pragma unroll
                for (int j = 0; j < 4; ++j) acc[k][j] = 0.f;
            const int d4 = (t & 31) * 4, s = t >> 5;
#pragma unroll
            for (int i2 = 0; i2 < 4; ++i2) {
                const int nn = (s << 4) + (i2 << 2);
                float vf[4][4];
#pragma unroll
                for (int i = 0; i < 4; ++i) {
                    ushort4 v4 = *(const ushort4*)&kvt[(nn + i) * 136 + d4];
                    vf[i][0] = bs2f(v4.x); vf[i][1] = bs2f(v4.y);
                    vf[i][2] = bs2f(v4.z); vf[i][3] = bs2f(v4.w);
                }
#pragma unroll
                for (int k = 0; k < 8; ++k) {
                    f32x4 a4 = *(const f32x4*)&at8[k][nn];
#pragma unroll
                    for (int i = 0; i < 4; ++i) {
                        acc[k][0] = fmaf(a4[i], vf[i][0], acc[k][0]);
                        acc[k][1] = fmaf(a4[i], vf[i][1], acc[k][1]);
                        acc[k][2] = fmaf(a4[i], vf[i][2], acc[k][2]);
                        acc[k][3] = fmaf(a4[i], vf[i][3], acc[k][3]);
                    }
                }
            }
            __syncthreads();   // compute done; scratch becomes red[]
#pragma unroll
            for (int k = 0; k < 8; ++k)
#pragma unroll
                for (int j = 0; j < 4; ++j)
                    acc[k][j] += __shfl_xor(acc[k][j], 32, 64);
            if (lane < 32) {
#pragma unroll
                for (int k = 0; k < 8; ++k)
#pragma unroll
                    for (int j = 0; j < 4; ++j)
                        red[(wv * 8 + k) * 132 + lane * 4 + j] = acc[k][j];
            }
            __syncthreads();
            for (int i = t; i < 1024; i += 512) {
                int k = i >> 7, d = i & 127;
                float ssum = 0.f;
#pragma unroll
                for (int w = 0; w < 8; ++w) ssum += red[(w * 8 + k) * 132 + d];
                upd_part[(((size_t)it * 64 + b) * 4 + qd) * 1024 + i] = ssum;
            }
        }

        // ---- GROUP BARRIER: partials visible -> arrival count -> spin
        __syncthreads();
        if (t == 0) {
            __threadfence();                       // release our stores
            atomicAdd(&bar[b], 1u);                // device-scope
            const unsigned target = 4u * (unsigned)(it + 1);
            while (__hip_atomic_load(&bar[b], __ATOMIC_RELAXED,
                                     __HIP_MEMORY_SCOPE_AGENT) < target) {
                __builtin_amdgcn_s_sleep(8);
            }
            __threadfence();                       // acquire peers' stores
        }
        __syncthreads();

        // ---- F: sum 4 quarter-partials, normalize by S
        if (t < 8) {
            size_t sb = ((size_t)it * 64 + b) * 32;
            S_[t] = S_part[sb + t] + S_part[sb + 8 + t]
                  + S_part[sb + 16 + t] + S_part[sb + 24 + t];
        }
        __syncthreads();
        for (int i = t; i < 1024; i += 512) {
            size_t ub = ((size_t)it * 64 + b) * 4096;
            float v = upd_part[ub + i] + upd_part[ub + 1024 + i]
                    + upd_part[ub + 2048 + i] + upd_part[ub + 3072 + i];
            u_[i >> 7][i & 127] = v / (S_[i >> 7] + 1e-8f);
        }
        __syncthreads();

        // ---- D: GRU gates via pre-transposed WTih/WThh (coalesced, t<384);
        //      thread j accumulates all 8 slot-rows. Gates -> scratch union.
        if (t < 384) {
            const int j = t;
            float accx[8], acch[8];
#pragma unroll
            for (int r = 0; r < 8; ++r) { accx[r] = 0.f; acch[r] = 0.f; }
            for (int c0 = 0; c0 < 128; c0 += 4) {
                float wx[4], wh[4];
#pragma unroll
                for (int e = 0; e < 4; ++e) {
                    wx[e] = WTih[(size_t)(c0 + e) * 384 + j];
                    wh[e] = WThh[(size_t)(c0 + e) * 384 + j];
                }
#pragma unroll
                for (int r = 0; r < 8; ++r) {
                    f32x4 u4 = *(const f32x4*)&u_[r][c0];
                    f32x4 h4 = *(const f32x4*)&sl[r][c0];
#pragma unroll
                    for (int e = 0; e < 4; ++e) {
                        accx[r] = fmaf(u4[e], wx[e], accx[r]);
                        acch[r] = fmaf(h4[e], wh[e], acch[r]);
                    }
                }
            }
            float bx = b_ih[j], bh = b_hh[j];
#pragma unroll
            for (int r = 0; r < 8; ++r) {
                gxb[r * 384 + j] = accx[r] + bx;
                ghb[r * 384 + j] = acch[r] + bh;
            }
        }
        __syncthreads();

        // ---- D2: combine gates (PyTorch order r,z,n)
#pragma unroll
        for (int e = 0; e < 2; ++e) {
            int idx = t + (e << 9);       // 0..1023
            int row = idx >> 7, d = idx & 127;
            float r = sigmoidf_(gxb[row * 384 + d] + ghb[row * 384 + d]);
            float z = sigmoidf_(gxb[row * 384 + 128 + d] + ghb[row * 384 + 128 + d]);
            float nv = tanhf(gxb[row * 384 + 256 + d] + r * ghb[row * 384 + 256 + d]);
            sn_[row][d] = (1.f - z) * nv + z * sl[row][d];
        }
        __syncthreads();

        // ---- LN(sn_) for MLP
        {
            float v0 = sn_[wv][lane], v1 = sn_[wv][lane + 64];
            float s = v0 + v1, s2 = v0 * v0 + v1 * v1;
            for (int off = 32; off > 0; off >>= 1) {
                s += __shfl_down(s, off, 64);
                s2 += __shfl_down(s2, off, 64);
            }
            if (lane == 0) {
                float mean = s * (1.f / 128.f);
                float var = s2 * (1.f / 128.f) - mean * mean;
                mrs_[wv][0] = mean; mrs_[wv][1] = rsqrtf(var + 1e-5f);
            }
        }
        __syncthreads();
        for (int i = t; i < 1024; i += 512) {
            int k = i >> 7, d = i & 127;
            u_[k][d] = (sn_[k][d] - mrs_[k][0]) * mrs_[k][1] * g_mlp[d] + b_mlp[d];
        }
        __syncthreads();

        // ---- MLP1: hm = gelu(u_ @ W1 + b1)
        {
            const int j = t & 127, kk = t >> 7;
            const int k0 = kk, k1 = kk + 4;
            float a00 = 0.f, a01 = 0.f, a10 = 0.f, a11 = 0.f;
            for (int c0 = 0; c0 < 128; c0 += 4) {
                f32x4 t0 = *(const f32x4*)&u_[k0][c0];
                f32x4 t1 = *(const f32x4*)&u_[k1][c0];
#pragma unroll
                for (int e = 0; e < 4; ++e) {
                    float w0 = W1[(size_t)(c0 + e) * 256 + j];
                    float w1 = W1[(size_t)(c0 + e) * 256 + j + 128];
                    a00 = fmaf(t0[e], w0, a00);
                    a01 = fmaf(t0[e], w1, a01);
                    a10 = fmaf(t1[e], w0, a10);
                    a11 = fmaf(t1[e], w1, a11);
                }
            }
            hm_[k0][j] = gelu_exact(a00 + b1[j]);
            hm_[k0][j + 128] = gelu_exact(a01 + b1[j + 128]);
            hm_[k1][j] = gelu_exact(a10 + b1[j]);
            hm_[k1][j + 128] = gelu_exact(a11 + b1[j + 128]);
        }
        __syncthreads();

        // ---- MLP2 + residual
        {
            const int d = t & 127, kk = t >> 7;
            const int k0 = kk, k1 = kk + 4;
            float a0 = sn_[k0][d] + b2[d];
            float a1 = sn_[k1][d] + b2[d];
            for (int j0 = 0; j0 < 256; j0 += 4) {
                f32x4 h0 = *(const f32x4*)&hm_[k0][j0];
                f32x4 h1 = *(const f32x4*)&hm_[k1][j0];
#pragma unroll
                for (int e = 0; e < 4; ++e) {
                    float w = W2[(size_t)(j0 + e) * 128 + d];
                    a0 = fmaf(h0[e], w, a0);
                    a1 = fmaf(h1[e], w, a1);
                }
            }
            sl[k0][d] = a0;
            sl[k1][d] = a1;
            if (last && qd == 0) {
                out_slots[((size_t)b * K_ + k0) * D_ + d] = a0;
                out_slots[((size_t)b * K_ + k1) * D_ + d] = a1;
            }
        }
        __syncthreads();
    }
}

// ---------------------------------------------------------------------------
extern "C" void kernel_launch(void* const* d_in, const int* in_sizes, int n_in,
                              void* d_out, int out_size, void* d_ws, size_t ws_size,
                              hipStream_t stream) {
    const float* x       = (const float*)d_in[0];
    const float* noise   = (const float*)d_in[1];
    const float* slot_mu = (const float*)d_in[2];
    const float* slot_ls = (const float*)d_in[3];
    const float* Wp      = (const float*)d_in[4];
    const float* bp      = (const float*)d_in[5];
    const float* g_in    = (const float*)d_in[6];
    const float* b_in    = (const float*)d_in[7];
    const float* Wq      = (const float*)d_in[8];
    const float* bq      = (const float*)d_in[9];
    const float* Wk      = (const float*)d_in[10];
    const float* bk      = (const float*)d_in[11];
    const float* Wv      = (const float*)d_in[12];
    const float* bv      = (const float*)d_in[13];
    const float* W_ih    = (const float*)d_in[14];
    const float* W_hh    = (const float*)d_in[15];
    const float* b_ih    = (const float*)d_in[16];
    const float* b_hh    = (const float*)d_in[17];
    const float* W1      = (const float*)d_in[18];
    const float* b1      = (const float*)d_in[19];
    const float* W2      = (const float*)d_in[20];
    const float* b2      = (const float*)d_in[21];
    const float* g_slots = (const float*)d_in[22];
    const float* b_slots = (const float*)d_in[23];
    const float* g_mlp   = (const float*)d_in[24];
    const float* b_mlp   = (const float*)d_in[25];

    float* out_slots = (float*)d_out;            // [64,8,128] fp32
    float* out_attn  = (float*)d_out + 65536;    // [64,8,1024] fp32

    // workspace layout (float units)
    float* wsf = (float*)d_ws;
    ushort_t* inputsb = (ushort_t*)wsf;                    // 65536x128 bf16
    ushort_t* kb = (ushort_t*)(wsf + 4194304);             // 65536x128 bf16
    ushort_t* vb = (ushort_t*)(wsf + 8388608);             // 65536x128 bf16
    ushort_t* WpT = (ushort_t*)(wsf + 13304320);  // 128x512 bf16
    ushort_t* WkT = (ushort_t*)(wsf + 13337088);  // 128x128 bf16
    ushort_t* WvT = (ushort_t*)(wsf + 13345280);  // 128x128 bf16
    float* WTih = wsf + 13353472;    // 128x384 fp32
    float* WThh = wsf + 13402624;    // 128x384 fp32
    unsigned* bar = (unsigned*)(wsf + 13451776); // 64 u32 barrier counters
    float* S_part = wsf + 13451840;  // [3][64][4][8]
    float* upd_part = wsf + 13457984; // [3][64][4][1024]

    prep_weights<<<dim3(256), dim3(256), 0, stream>>>(
        Wp, Wk, Wv, W_ih, W_hh, WpT, WkT, WvT, WTih, WThh, bar);
    proj_ln_mfma<<<dim3(1024), dim3(256), 0, stream>>>(x, WpT, bp, g_in, b_in, inputsb);
    kv_mfma<<<dim3(1024), dim3(256), 0, stream>>>(inputsb, WkT, bk, WvT, bv, kb, vb);

    fused_slots<<<dim3(256), dim3(512), 0, stream>>>(
        kb, vb, noise, slot_mu, slot_ls, g_slots, b_slots, Wq, bq,
        WTih, WThh, b_ih, b_hh, W1, b1, W2, b2, g_mlp, b_mlp,
        upd_part, S_part, bar, out_slots, out_attn);
}

// Round 6
// 407.862 us; speedup vs baseline: 3.1842x; 3.1842x over previous
//
#include <hip/hip_runtime.h>
#include <hip/hip_bf16.h>
#include <math.h>

#define B_ 64
#define C_ 512
#define N_ 1024
#define D_ 128
#define K_ 8

typedef __attribute__((ext_vector_type(8))) short bf16x8;  // 8 bf16 = 4 VGPRs
typedef __attribute__((ext_vector_type(4))) float f32x4;
typedef unsigned short ushort_t;

__device__ __forceinline__ unsigned short f2bs(float f) {
    union { __hip_bfloat16 h; unsigned short s; } u;
    u.h = __float2bfloat16(f);
    return u.s;
}
__device__ __forceinline__ float bs2f(unsigned short s) {
    union { unsigned int u; float f; } v;
    v.u = ((unsigned int)s) << 16;
    return v.f;
}
__device__ __forceinline__ float sigmoidf_(float x) { return 1.0f / (1.0f + expf(-x)); }
__device__ __forceinline__ float gelu_exact(float x) {
    return 0.5f * x * (1.0f + erff(x * 0.7071067811865476f));
}

// ---------------------------------------------------------------------------
// K0: weight prep (unchanged, proven).
// ---------------------------------------------------------------------------
__global__ __launch_bounds__(256) void prep_weights(
    const float* __restrict__ Wp, const float* __restrict__ Wk,
    const float* __restrict__ Wv, const float* __restrict__ W_ih,
    const float* __restrict__ W_hh,
    ushort_t* __restrict__ WpT, ushort_t* __restrict__ WkT,
    ushort_t* __restrict__ WvT, float* __restrict__ WTih,
    float* __restrict__ WThh)
{
    int tid = blockIdx.x * 256 + threadIdx.x;   // grid 256*256 = 65536
    {
        int c = tid >> 7, d = tid & 127;        // coalesced read of Wp
        WpT[d * 512 + c] = f2bs(Wp[tid]);
    }
    if (tid < 16384) {
        int c = tid >> 7, d = tid & 127;
        WkT[d * 128 + c] = f2bs(Wk[tid]);
        WvT[d * 128 + c] = f2bs(Wv[tid]);
    }
    if (tid < 49152) {
        int j = tid >> 7, c = tid & 127;        // coalesced read of W_ih
        WTih[c * 384 + j] = W_ih[tid];
        WThh[c * 384 + j] = W_hh[tid];
    }
}

// ---------------------------------------------------------------------------
// K1: inputs = LN(x_flat @ Wp + bp)*g+b via MFMA bf16 (unchanged, proven).
// ---------------------------------------------------------------------------
__global__ __launch_bounds__(256) void proj_ln_mfma(
    const float* __restrict__ x, const ushort_t* __restrict__ WpT,
    const float* __restrict__ bp, const float* __restrict__ g_in,
    const float* __restrict__ b_in, ushort_t* __restrict__ outb)
{
    __shared__ ushort_t Al[64 * 40];
    __shared__ ushort_t Bl[128 * 40];
    __shared__ float red[64][2][2];
    const int t = threadIdx.x;
    const int b = blockIdx.x >> 4;
    const int n0 = (blockIdx.x & 15) << 6;
    const int w = t >> 6, lane = t & 63;
    const int quad = lane >> 4, m = lane & 15;
    const int rowoff = (w >> 1) << 5;   // 0 / 32
    const int coloff = (w & 1) << 6;    // 0 / 64

    f32x4 acc[2][4];
#pragma unroll
    for (int r = 0; r < 2; ++r)
#pragma unroll
        for (int c = 0; c < 4; ++c) acc[r][c] = (f32x4){0.f, 0.f, 0.f, 0.f};

    const float* xb = x + (size_t)b * (C_ * N_);
    for (int c0 = 0; c0 < C_; c0 += 32) {
#pragma unroll
        for (int i = 0; i < 8; ++i) {
            int idx = t + (i << 8);
            int cc = idx >> 6, nn = idx & 63;
            Al[nn * 40 + cc] = f2bs(xb[(size_t)(c0 + cc) * N_ + n0 + nn]);
        }
#pragma unroll
        for (int i = 0; i < 2; ++i) {
            int idx = t + (i << 8);           // 0..511
            int d = idx >> 2, seg = idx & 3;  // 128 rows x 4 segs of 8
            *(bf16x8*)&Bl[d * 40 + seg * 8] =
                *(const bf16x8*)&WpT[d * 512 + c0 + seg * 8];
        }
        __syncthreads();
        bf16x8 af[2], bfr[4];
#pragma unroll
        for (int r = 0; r < 2; ++r)
            af[r] = *(const bf16x8*)&Al[(rowoff + 16 * r + m) * 40 + quad * 8];
#pragma unroll
        for (int c = 0; c < 4; ++c)
            bfr[c] = *(const bf16x8*)&Bl[(coloff + 16 * c + m) * 40 + quad * 8];
#pragma unroll
        for (int r = 0; r < 2; ++r)
#pragma unroll
            for (int c = 0; c < 4; ++c)
                acc[r][c] = __builtin_amdgcn_mfma_f32_16x16x32_bf16(af[r], bfr[c], acc[r][c], 0, 0, 0);
        __syncthreads();
    }
    float gv[4], bv[4], bpv[4];
#pragma unroll
    for (int c = 0; c < 4; ++c) {
        int col = coloff + 16 * c + m;
        bpv[c] = bp[col]; gv[c] = g_in[col]; bv[c] = b_in[col];
    }
#pragma unroll
    for (int r = 0; r < 2; ++r)
#pragma unroll
        for (int c = 0; c < 4; ++c)
#pragma unroll
            for (int g = 0; g < 4; ++g) acc[r][c][g] += bpv[c];

#pragma unroll
    for (int r = 0; r < 2; ++r) {
#pragma unroll
        for (int g = 0; g < 4; ++g) {
            float s = 0.f, s2 = 0.f;
#pragma unroll
            for (int c = 0; c < 4; ++c) { float v = acc[r][c][g]; s += v; s2 += v * v; }
#pragma unroll
            for (int off = 1; off < 16; off <<= 1) {
                s += __shfl_xor(s, off, 64);
                s2 += __shfl_xor(s2, off, 64);
            }
            if (m == 0) {
                int row = rowoff + 16 * r + quad * 4 + g;
                red[row][w & 1][0] = s;
                red[row][w & 1][1] = s2;
            }
        }
    }
    __syncthreads();
#pragma unroll
    for (int r = 0; r < 2; ++r) {
#pragma unroll
        for (int g = 0; g < 4; ++g) {
            int row = rowoff + 16 * r + quad * 4 + g;
            float s = red[row][0][0] + red[row][1][0];
            float s2 = red[row][0][1] + red[row][1][1];
            float mean = s * (1.f / 128.f);
            float var = s2 * (1.f / 128.f) - mean * mean;
            float rs = rsqrtf(var + 1e-5f);
            size_t base = ((size_t)b * N_ + n0 + row) * D_;
#pragma unroll
            for (int c = 0; c < 4; ++c) {
                int col = coloff + 16 * c + m;
                float v = (acc[r][c][g] - mean) * rs * gv[c] + bv[c];
                outb[base + col] = f2bs(v);
            }
        }
    }
}

// ---------------------------------------------------------------------------
// K2: k/v = A@Wk/Wv + bias (unchanged, proven).
// ---------------------------------------------------------------------------
__global__ __launch_bounds__(256) void kv_mfma(
    const ushort_t* __restrict__ A,
    const ushort_t* __restrict__ WkT, const float* __restrict__ bk,
    const ushort_t* __restrict__ WvT, const float* __restrict__ bv,
    ushort_t* __restrict__ kout, ushort_t* __restrict__ vout)
{
    __shared__ ushort_t Al[64 * 40];
    __shared__ ushort_t Bk[128 * 40];
    __shared__ ushort_t Bv[128 * 40];
    const int t = threadIdx.x;
    const int row0 = blockIdx.x << 6;
    const int w = t >> 6, lane = t & 63;
    const int quad = lane >> 4, m = lane & 15;
    const int is_v = w >> 1;
    const int rowoff = (w & 1) << 5;

    f32x4 acc[2][8];
#pragma unroll
    for (int r = 0; r < 2; ++r)
#pragma unroll
        for (int c = 0; c < 8; ++c) acc[r][c] = (f32x4){0.f, 0.f, 0.f, 0.f};

    for (int c0 = 0; c0 < D_; c0 += 32) {
#pragma unroll
        for (int i = 0; i < 2; ++i) {
            int idx = t + (i << 8);
            int rr = idx >> 3, cc4 = (idx & 7) << 2;
            *(ushort4*)&Al[rr * 40 + cc4] =
                *(const ushort4*)&A[(size_t)(row0 + rr) * D_ + c0 + cc4];
        }
#pragma unroll
        for (int i = 0; i < 2; ++i) {
            int idx = t + (i << 8);
            int d = idx >> 2, seg = idx & 3;
            *(bf16x8*)&Bk[d * 40 + seg * 8] =
                *(const bf16x8*)&WkT[d * 128 + c0 + seg * 8];
            *(bf16x8*)&Bv[d * 40 + seg * 8] =
                *(const bf16x8*)&WvT[d * 128 + c0 + seg * 8];
        }
        __syncthreads();
        const ushort_t* Bsrc = is_v ? Bv : Bk;
        bf16x8 af[2], bfr[8];
#pragma unroll
        for (int r = 0; r < 2; ++r)
            af[r] = *(const bf16x8*)&Al[(rowoff + 16 * r + m) * 40 + quad * 8];
#pragma unroll
        for (int c = 0; c < 8; ++c)
            bfr[c] = *(const bf16x8*)&Bsrc[(16 * c + m) * 40 + quad * 8];
#pragma unroll
        for (int r = 0; r < 2; ++r)
#pragma unroll
            for (int c = 0; c < 8; ++c)
                acc[r][c] = __builtin_amdgcn_mfma_f32_16x16x32_bf16(af[r], bfr[c], acc[r][c], 0, 0, 0);
        __syncthreads();
    }
    const float* bias = is_v ? bv : bk;
    ushort_t* dst = is_v ? vout : kout;
    float bval[8];
#pragma unroll
    for (int c = 0; c < 8; ++c) bval[c] = bias[16 * c + m];
#pragma unroll
    for (int r = 0; r < 2; ++r) {
#pragma unroll
        for (int g = 0; g < 4; ++g) {
            int row = rowoff + 16 * r + quad * 4 + g;
            size_t base = (size_t)(row0 + row) * D_;
#pragma unroll
            for (int c = 0; c < 8; ++c)
                dst[base + 16 * c + m] = f2bs(acc[r][c][g] + bval[c]);
        }
    }
}

// ---------------------------------------------------------------------------
// K3: slots init + iteration-0 q (round-0 q_ln pattern; no zeroing needed).
// ---------------------------------------------------------------------------
__global__ __launch_bounds__(128) void init_q(
    const float* __restrict__ noise, const float* __restrict__ mu,
    const float* __restrict__ lsig,
    const float* __restrict__ g_slots, const float* __restrict__ b_slots,
    const float* __restrict__ Wq, const float* __restrict__ bq,
    float* __restrict__ slots, float* __restrict__ qbuf)
{
    __shared__ float sl[128], sl2[128];
    __shared__ float mrs[2];
    const int t = threadIdx.x;
    const int row = blockIdx.x;        // b*8 + k
    const int b = row >> 3;
    const int kd = (row & 7) * 128 + t;
    float sv = mu[kd] + expf(lsig[kd]) * noise[b * 1024 + kd];
    slots[(size_t)row * D_ + t] = sv;
    sl[t] = sv;
    __syncthreads();
    if (t < 64) {
        float v0 = sl[t], v1 = sl[t + 64];
        float s = v0 + v1, s2 = v0 * v0 + v1 * v1;
        for (int off = 32; off > 0; off >>= 1) {
            s += __shfl_down(s, off, 64);
            s2 += __shfl_down(s2, off, 64);
        }
        if (t == 0) {
            float mean = s * (1.f / 128.f);
            float var = s2 * (1.f / 128.f) - mean * mean;
            mrs[0] = mean; mrs[1] = rsqrtf(var + 1e-5f);
        }
    }
    __syncthreads();
    sl2[t] = (sl[t] - mrs[0]) * mrs[1] * g_slots[t] + b_slots[t];
    __syncthreads();
    float a = bq[t];
    for (int c = 0; c < 128; ++c) a = fmaf(sl2[c], Wq[(size_t)c * D_ + t], a);
    qbuf[(size_t)row * D_ + t] = a;
}

// ---------------------------------------------------------------------------
// K4: attn + PV fused per n-quarter. Grid (4,64) x 512 thr. Softmax over K=8
// is per-n local -> no cross-block reduction. Logits/softmax/PV/red-tree are
// v4's correctness-proven blocks; q read from qbuf; plain partial stores
// (no atomics, no zeroing, no group barrier).
// ---------------------------------------------------------------------------
__global__ __launch_bounds__(512, 2) void attn_pv(
    const ushort_t* __restrict__ kb, const ushort_t* __restrict__ vb,
    const float* __restrict__ qbuf,
    float* __restrict__ S_part, float* __restrict__ upd_part,
    float* __restrict__ out_attn, int last)
{
    __shared__ __align__(16) char scratch[69632];   // kvt[256][136] ush U red[64][132] f32
    __shared__ __align__(16) float at8[8][264];     // logits -> attn (quarter)
    __shared__ __align__(16) float qs[8][132];
    __shared__ float red2[4][8];
    ushort_t* kvt = (ushort_t*)scratch;
    float* red = (float*)scratch;

    const int t = threadIdx.x;
    const int qd = blockIdx.x, b = blockIdx.y;
    const int nbase = qd << 8;
    const int wv = t >> 6, lane = t & 63;
    const float SCALE = 0.08838834764831845f;

    // q: 4 KB, coalesced
    for (int i = t; i < 1024; i += 512)
        qs[i >> 7][i & 127] = qbuf[(size_t)b * 1024 + i];
    // stage k-quarter (coalesced bf16x8)
#pragma unroll
    for (int i = 0; i < 8; ++i) {
        int idx = t + (i << 9);            // 0..4095
        int rr = idx >> 4, u8 = (idx & 15) << 3;
        *(bf16x8*)&kvt[rr * 136 + u8] =
            *(const bf16x8*)&kb[((size_t)b * N_ + nbase + rr) * D_ + u8];
    }
    __syncthreads();

    // logits: thread (rr = t&255, kh = t>>8) -> 4 k-dots for its n-row
    {
        const int rr = t & 255, kh = t >> 8;
        float acc[4] = {0.f, 0.f, 0.f, 0.f};
        for (int c0 = 0; c0 < 128; c0 += 8) {
            bf16x8 kr = *(const bf16x8*)&kvt[rr * 136 + c0];
            float kf[8];
#pragma unroll
            for (int j = 0; j < 8; ++j) kf[j] = bs2f((ushort_t)kr[j]);
#pragma unroll
            for (int kk = 0; kk < 4; ++kk) {
                f32x4 qa = *(const f32x4*)&qs[4 * kh + kk][c0];
                f32x4 qb = *(const f32x4*)&qs[4 * kh + kk][c0 + 4];
                acc[kk] = fmaf(qa[0], kf[0], acc[kk]);
                acc[kk] = fmaf(qa[1], kf[1], acc[kk]);
                acc[kk] = fmaf(qa[2], kf[2], acc[kk]);
                acc[kk] = fmaf(qa[3], kf[3], acc[kk]);
                acc[kk] = fmaf(qb[0], kf[4], acc[kk]);
                acc[kk] = fmaf(qb[1], kf[5], acc[kk]);
                acc[kk] = fmaf(qb[2], kf[6], acc[kk]);
                acc[kk] = fmaf(qb[3], kf[7], acc[kk]);
            }
        }
#pragma unroll
        for (int kk = 0; kk < 4; ++kk)
            at8[4 * kh + kk][rr] = acc[kk];
    }
    __syncthreads();

    // softmax over k per local n (t<256) + per-wave S partials
    if (t < 256) {
        float l[8];
#pragma unroll
        for (int k = 0; k < 8; ++k) l[k] = at8[k][t] * SCALE;
        float mx = l[0];
#pragma unroll
        for (int k = 1; k < 8; ++k) mx = fmaxf(mx, l[k]);
        float e[8], ssum = 0.f;
#pragma unroll
        for (int k = 0; k < 8; ++k) { e[k] = expf(l[k] - mx); ssum += e[k]; }
        float inv = 1.f / ssum;
        float p[8];
#pragma unroll
        for (int k = 0; k < 8; ++k) {
            p[k] = e[k] * inv;
            at8[k][t] = p[k];
            if (last) out_attn[((size_t)b * K_ + k) * N_ + nbase + t] = p[k];
        }
#pragma unroll
        for (int k = 0; k < 8; ++k) {
            float v = p[k];
            for (int off = 32; off > 0; off >>= 1) v += __shfl_down(v, off, 64);
            if (lane == 0) red2[wv][k] = v;
        }
    }
    __syncthreads();
    if (t < 8)
        S_part[((size_t)b * 4 + qd) * 8 + t] =
            red2[0][t] + red2[1][t] + red2[2][t] + red2[3][t];

    // stage v-quarter (kvt reuse; logits reads finished before prior sync)
#pragma unroll
    for (int i = 0; i < 8; ++i) {
        int idx = t + (i << 9);
        int rr = idx >> 4, u8 = (idx & 15) << 3;
        *(bf16x8*)&kvt[rr * 136 + u8] =
            *(const bf16x8*)&vb[((size_t)b * N_ + nbase + rr) * D_ + u8];
    }
    __syncthreads();

    // PV: upd quarter-partial = attn(quarter) @ v(quarter)  [v4-proven]
    {
        float acc[8][4];
#pragma unroll
        for (int k = 0; k < 8; ++k)
#pragma unroll
            for (int j = 0; j < 4; ++j) acc[k][j] = 0.f;
        const int d4 = (t & 31) * 4, s = t >> 5;
#pragma unroll
        for (int i2 = 0; i2 < 4; ++i2) {
            const int nn = (s << 4) + (i2 << 2);
            float vf[4][4];
#pragma unroll
            for (int i = 0; i < 4; ++i) {
                ushort4 v4 = *(const ushort4*)&kvt[(nn + i) * 136 + d4];
                vf[i][0] = bs2f(v4.x); vf[i][1] = bs2f(v4.y);
                vf[i][2] = bs2f(v4.z); vf[i][3] = bs2f(v4.w);
            }
#pragma unroll
            for (int k = 0; k < 8; ++k) {
                f32x4 a4 = *(const f32x4*)&at8[k][nn];
#pragma unroll
                for (int i = 0; i < 4; ++i) {
                    acc[k][0] = fmaf(a4[i], vf[i][0], acc[k][0]);
                    acc[k][1] = fmaf(a4[i], vf[i][1], acc[k][1]);
                    acc[k][2] = fmaf(a4[i], vf[i][2], acc[k][2]);
                    acc[k][3] = fmaf(a4[i], vf[i][3], acc[k][3]);
                }
            }
        }
        __syncthreads();   // kvt reads done; scratch becomes red[]
#pragma unroll
        for (int k = 0; k < 8; ++k)
#pragma unroll
            for (int j = 0; j < 4; ++j)
                acc[k][j] += __shfl_xor(acc[k][j], 32, 64);
        if (lane < 32) {
#pragma unroll
            for (int k = 0; k < 8; ++k)
#pragma unroll
                for (int j = 0; j < 4; ++j)
                    red[(wv * 8 + k) * 132 + lane * 4 + j] = acc[k][j];
        }
        __syncthreads();
        for (int i = t; i < 1024; i += 512) {
            int k = i >> 7, d = i & 127;
            float ssum = 0.f;
#pragma unroll
            for (int w = 0; w < 8; ++w) ssum += red[(w * 8 + k) * 132 + d];
            upd_part[((size_t)b * 4 + qd) * 1024 + i] = ssum;
        }
    }
}

// ---------------------------------------------------------------------------
// K5: GRU + LN + MLP + residual (round-0 proven body) + partial-sum entry
// + next-iteration q tail. Grid 512 x 256 thr (one block per slot-row).
// ---------------------------------------------------------------------------
__global__ __launch_bounds__(256) void gru_mlp_q(
    const float* __restrict__ upd_part, const float* __restrict__ S_part,
    float* __restrict__ slots,
    const float* __restrict__ WTih, const float* __restrict__ WThh,
    const float* __restrict__ b_ih, const float* __restrict__ b_hh,
    const float* __restrict__ W1, const float* __restrict__ b1,
    const float* __restrict__ W2, const float* __restrict__ b2,
    const float* __restrict__ g_mlp, const float* __restrict__ b_mlp,
    const float* __restrict__ g_slots, const float* __restrict__ b_slots,
    const float* __restrict__ Wq, const float* __restrict__ bq,
    float* __restrict__ qbuf,
    float* __restrict__ out_slots, int final_iter)
{
    __shared__ float u[128], h[128], gx[384], gh[384], sn[128], tt[128], hm[256];
    __shared__ float mrs[2];
    const int t = threadIdx.x;
    const int row = blockIdx.x;           // b*8 + k
    const int b = row >> 3, k = row & 7;
    if (t < 128) {
        size_t sb = (size_t)b * 4;
        float S = S_part[(sb + 0) * 8 + k] + S_part[(sb + 1) * 8 + k]
                + S_part[(sb + 2) * 8 + k] + S_part[(sb + 3) * 8 + k];
        float inv = 1.0f / (S + 1e-8f);
        int i = k * 128 + t;
        float up = upd_part[(sb + 0) * 1024 + i] + upd_part[(sb + 1) * 1024 + i]
                 + upd_part[(sb + 2) * 1024 + i] + upd_part[(sb + 3) * 1024 + i];
        u[t] = up * inv;
        h[t] = slots[(size_t)row * D_ + t];
    }
    __syncthreads();
    {
        int j = t;
        float ax = 0.f, ah = 0.f;
        for (int c = 0; c < 128; ++c) {
            float uc = u[c], hc = h[c];
            ax = fmaf(uc, WTih[(size_t)c * 384 + j], ax);
            ah = fmaf(hc, WThh[(size_t)c * 384 + j], ah);
        }
        gx[j] = ax + b_ih[j];
        gh[j] = ah + b_hh[j];
    }
    if (t < 128) {
        int j = 256 + t;
        float ax = 0.f, ah = 0.f;
        for (int c = 0; c < 128; ++c) {
            float uc = u[c], hc = h[c];
            ax = fmaf(uc, WTih[(size_t)c * 384 + j], ax);
            ah = fmaf(hc, WThh[(size_t)c * 384 + j], ah);
        }
        gx[j] = ax + b_ih[j];
        gh[j] = ah + b_hh[j];
    }
    __syncthreads();
    if (t < 128) {
        float r = sigmoidf_(gx[t] + gh[t]);
        float z = sigmoidf_(gx[t + 128] + gh[t + 128]);
        float nv = tanhf(gx[t + 256] + r * gh[t + 256]);
        sn[t] = (1.0f - z) * nv + z * h[t];
    }
    __syncthreads();
    if (t < 64) {
        float v0 = sn[t], v1 = sn[t + 64];
        float s = v0 + v1, s2 = v0 * v0 + v1 * v1;
        for (int off = 32; off > 0; off >>= 1) {
            s += __shfl_down(s, off, 64);
            s2 += __shfl_down(s2, off, 64);
        }
        if (t == 0) {
            float mean = s * (1.f / 128.f);
            float var = s2 * (1.f / 128.f) - mean * mean;
            mrs[0] = mean; mrs[1] = rsqrtf(var + 1e-5f);
        }
    }
    __syncthreads();
    if (t < 128) tt[t] = (sn[t] - mrs[0]) * mrs[1] * g_mlp[t] + b_mlp[t];
    __syncthreads();
    {
        float a = 0.f;
        for (int c = 0; c < 128; ++c) a = fmaf(tt[c], W1[(size_t)c * 256 + t], a);
        hm[t] = gelu_exact(a + b1[t]);
    }
    __syncthreads();
    if (t < 128) {
        float a = sn[t] + b2[t];
        for (int j = 0; j < 256; ++j) a = fmaf(hm[j], W2[(size_t)j * D_ + t], a);
        slots[(size_t)row * D_ + t] = a;
        if (final_iter) out_slots[(size_t)row * D_ + t] = a;
        u[t] = a;                      // reuse u[] as new-slots buffer for q
    }
    __syncthreads();
    // ---- q for next iteration: q = LN(slots_new)*g_slots+b_slots @ Wq + bq
    if (t < 64) {
        float v0 = u[t], v1 = u[t + 64];
        float s = v0 + v1, s2 = v0 * v0 + v1 * v1;
        for (int off = 32; off > 0; off >>= 1) {
            s += __shfl_down(s, off, 64);
            s2 += __shfl_down(s2, off, 64);
        }
        if (t == 0) {
            float mean = s * (1.f / 128.f);
            float var = s2 * (1.f / 128.f) - mean * mean;
            mrs[0] = mean; mrs[1] = rsqrtf(var + 1e-5f);
        }
    }
    __syncthreads();
    if (t < 128) tt[t] = (u[t] - mrs[0]) * mrs[1] * g_slots[t] + b_slots[t];
    __syncthreads();
    if (!final_iter && t < 128) {
        float a = bq[t];
        for (int c = 0; c < 128; ++c) a = fmaf(tt[c], Wq[(size_t)c * D_ + t], a);
        qbuf[(size_t)row * D_ + t] = a;
    }
}

// ---------------------------------------------------------------------------
extern "C" void kernel_launch(void* const* d_in, const int* in_sizes, int n_in,
                              void* d_out, int out_size, void* d_ws, size_t ws_size,
                              hipStream_t stream) {
    const float* x       = (const float*)d_in[0];
    const float* noise   = (const float*)d_in[1];
    const float* slot_mu = (const float*)d_in[2];
    const float* slot_ls = (const float*)d_in[3];
    const float* Wp      = (const float*)d_in[4];
    const float* bp      = (const float*)d_in[5];
    const float* g_in    = (const float*)d_in[6];
    const float* b_in    = (const float*)d_in[7];
    const float* Wq      = (const float*)d_in[8];
    const float* bq      = (const float*)d_in[9];
    const float* Wk      = (const float*)d_in[10];
    const float* bk      = (const float*)d_in[11];
    const float* Wv      = (const float*)d_in[12];
    const float* bv      = (const float*)d_in[13];
    const float* W_ih    = (const float*)d_in[14];
    const float* W_hh    = (const float*)d_in[15];
    const float* b_ih    = (const float*)d_in[16];
    const float* b_hh    = (const float*)d_in[17];
    const float* W1      = (const float*)d_in[18];
    const float* b1      = (const float*)d_in[19];
    const float* W2      = (const float*)d_in[20];
    const float* b2      = (const float*)d_in[21];
    const float* g_slots = (const float*)d_in[22];
    const float* b_slots = (const float*)d_in[23];
    const float* g_mlp   = (const float*)d_in[24];
    const float* b_mlp   = (const float*)d_in[25];

    float* out_slots = (float*)d_out;            // [64,8,128] fp32
    float* out_attn  = (float*)d_out + 65536;    // [64,8,1024] fp32

    // workspace layout (float units)
    float* wsf = (float*)d_ws;
    ushort_t* inputsb = (ushort_t*)wsf;                    // 65536x128 bf16
    ushort_t* kb = (ushort_t*)(wsf + 4194304);             // 65536x128 bf16
    ushort_t* vb = (ushort_t*)(wsf + 8388608);             // 65536x128 bf16
    float* slots    = wsf + 12582912;   // 512*128
    float* qbuf     = wsf + 12648448;   // 512*128
    float* upd_part = wsf + 12713984;   // [64][4][8][128] = 262144
    float* S_part   = wsf + 12976128;   // [64][4][8] = 2048
    ushort_t* WpT = (ushort_t*)(wsf + 13304320);  // 128x512 bf16
    ushort_t* WkT = (ushort_t*)(wsf + 13337088);  // 128x128 bf16
    ushort_t* WvT = (ushort_t*)(wsf + 13345280);  // 128x128 bf16
    float* WTih = wsf + 13353472;    // 128x384 fp32
    float* WThh = wsf + 13402624;    // 128x384 fp32

    prep_weights<<<dim3(256), dim3(256), 0, stream>>>(
        Wp, Wk, Wv, W_ih, W_hh, WpT, WkT, WvT, WTih, WThh);
    proj_ln_mfma<<<dim3(1024), dim3(256), 0, stream>>>(x, WpT, bp, g_in, b_in, inputsb);
    kv_mfma<<<dim3(1024), dim3(256), 0, stream>>>(inputsb, WkT, bk, WvT, bv, kb, vb);
    init_q<<<dim3(512), dim3(128), 0, stream>>>(
        noise, slot_mu, slot_ls, g_slots, b_slots, Wq, bq, slots, qbuf);

    for (int it = 0; it < 3; ++it) {
        int last = (it == 2) ? 1 : 0;
        attn_pv<<<dim3(4, 64), dim3(512), 0, stream>>>(
            kb, vb, qbuf, S_part, upd_part, out_attn, last);
        gru_mlp_q<<<dim3(512), dim3(256), 0, stream>>>(
            upd_part, S_part, slots, WTih, WThh, b_ih, b_hh,
            W1, b1, W2, b2, g_mlp, b_mlp, g_slots, b_slots,
            Wq, bq, qbuf, out_slots, last);
    }
}

// Round 7
// 396.130 us; speedup vs baseline: 3.2785x; 1.0296x over previous
//
#include <hip/hip_runtime.h>
#include <hip/hip_bf16.h>
#include <math.h>

#define B_ 64
#define C_ 512
#define N_ 1024
#define D_ 128
#define K_ 8

typedef __attribute__((ext_vector_type(8))) short bf16x8;  // 8 bf16 = 4 VGPRs
typedef __attribute__((ext_vector_type(4))) float f32x4;
typedef unsigned short ushort_t;

__device__ __forceinline__ unsigned short f2bs(float f) {
    union { __hip_bfloat16 h; unsigned short s; } u;
    u.h = __float2bfloat16(f);
    return u.s;
}
__device__ __forceinline__ float bs2f(unsigned short s) {
    union { unsigned int u; float f; } v;
    v.u = ((unsigned int)s) << 16;
    return v.f;
}
__device__ __forceinline__ float sigmoidf_(float x) { return 1.0f / (1.0f + expf(-x)); }
__device__ __forceinline__ float gelu_exact(float x) {
    return 0.5f * x * (1.0f + erff(x * 0.7071067811865476f));
}

// ---------------------------------------------------------------------------
// K0: weight prep (blocks 0-255, proven) + slots init / iter-0 q (blocks
// 256-511, 2 slot-rows per block). Merged to save one launch; the two paths
// are independent and branch at block granularity (no shared barriers).
// ---------------------------------------------------------------------------
__global__ __launch_bounds__(256) void prep_init(
    const float* __restrict__ Wp, const float* __restrict__ Wk,
    const float* __restrict__ Wv, const float* __restrict__ W_ih,
    const float* __restrict__ W_hh,
    const float* __restrict__ noise, const float* __restrict__ mu,
    const float* __restrict__ lsig,
    const float* __restrict__ g_slots, const float* __restrict__ b_slots,
    const float* __restrict__ Wq, const float* __restrict__ bq,
    ushort_t* __restrict__ WpT, ushort_t* __restrict__ WkT,
    ushort_t* __restrict__ WvT, float* __restrict__ WTih,
    float* __restrict__ WThh,
    float* __restrict__ slots, float* __restrict__ qbuf)
{
    __shared__ float sl2[2][128];
    __shared__ float tt2[2][128];
    __shared__ float mrs2[2][2];
    const int t = threadIdx.x;

    if (blockIdx.x < 256) {
        // ---- weight prep (proven round-0 body)
        int tid = blockIdx.x * 256 + t;             // 0..65535
        {
            int c = tid >> 7, d = tid & 127;        // coalesced read of Wp
            WpT[d * 512 + c] = f2bs(Wp[tid]);
        }
        if (tid < 16384) {
            int c = tid >> 7, d = tid & 127;
            WkT[d * 128 + c] = f2bs(Wk[tid]);
            WvT[d * 128 + c] = f2bs(Wv[tid]);
        }
        if (tid < 49152) {
            int j = tid >> 7, c = tid & 127;        // coalesced read of W_ih
            WTih[c * 384 + j] = W_ih[tid];
            WThh[c * 384 + j] = W_hh[tid];
        }
        return;
    }

    // ---- slots init + q for iteration 0 (2 rows per block)
    const int lr = t >> 7, lt = t & 127;
    const int row = ((blockIdx.x - 256) << 1) | lr;   // 0..511 = b*8+k
    const int b = row >> 3;
    const int kd = (row & 7) * 128 + lt;
    float sv = mu[kd] + expf(lsig[kd]) * noise[b * 1024 + kd];
    slots[(size_t)row * D_ + lt] = sv;
    sl2[lr][lt] = sv;
    __syncthreads();
    if (lt < 64) {     // wave 2*lr handles row lr's reduction
        float v0 = sl2[lr][lt], v1 = sl2[lr][lt + 64];
        float s = v0 + v1, s2 = v0 * v0 + v1 * v1;
        for (int off = 32; off > 0; off >>= 1) {
            s += __shfl_down(s, off, 64);
            s2 += __shfl_down(s2, off, 64);
        }
        if (lt == 0) {
            float mean = s * (1.f / 128.f);
            float var = s2 * (1.f / 128.f) - mean * mean;
            mrs2[lr][0] = mean; mrs2[lr][1] = rsqrtf(var + 1e-5f);
        }
    }
    __syncthreads();
    tt2[lr][lt] = (sl2[lr][lt] - mrs2[lr][0]) * mrs2[lr][1] * g_slots[lt] + b_slots[lt];
    __syncthreads();
    float a = bq[lt];
    for (int c = 0; c < 128; ++c) a = fmaf(tt2[lr][c], Wq[(size_t)c * D_ + lt], a);
    qbuf[(size_t)row * D_ + lt] = a;
}

// ---------------------------------------------------------------------------
// K1+K2 fused: inputs = LN(x@Wp+bp)*g+b -> LDS (bf16) -> k/v = inputs@Wk/Wv.
// Phase 1 is the proven proj_ln_mfma body (x staging vectorized to float4);
// the epilogue writes A2[64][136] in LDS instead of global inputsb. Phase 2
// is the proven kv_mfma loop reading A-fragments from A2 (pitch 136 = the
// conflict-free pattern measured 0-conflict in kvt). Saves the 32 MB
// inputsb round-trip + one launch + K2's A-staging.
// ---------------------------------------------------------------------------
__global__ __launch_bounds__(256) void proj_kv(
    const float* __restrict__ x, const ushort_t* __restrict__ WpT,
    const float* __restrict__ bp, const float* __restrict__ g_in,
    const float* __restrict__ b_in,
    const ushort_t* __restrict__ WkT, const float* __restrict__ bk,
    const ushort_t* __restrict__ WvT, const float* __restrict__ bv,
    ushort_t* __restrict__ kout, ushort_t* __restrict__ vout)
{
    __shared__ __align__(16) ushort_t Al[64 * 40];
    __shared__ __align__(16) ushort_t Bl[128 * 40];   // WpT chunks, then WkT chunks
    __shared__ __align__(16) ushort_t Bv2[128 * 40];  // WvT chunks (phase 2)
    __shared__ __align__(16) ushort_t A2[64 * 136];   // LN'd inputs, bf16, full row
    __shared__ float red[64][2][2];
    const int t = threadIdx.x;
    const int b = blockIdx.x >> 4;
    const int n0 = (blockIdx.x & 15) << 6;
    const int w = t >> 6, lane = t & 63;
    const int quad = lane >> 4, m = lane & 15;
    const int rowoff = (w >> 1) << 5;   // 0 / 32
    const int coloff = (w & 1) << 6;    // 0 / 64

    // ================= phase 1: proj + LN (proven) =================
    f32x4 acc[2][4];
#pragma unroll
    for (int r = 0; r < 2; ++r)
#pragma unroll
        for (int c = 0; c < 4; ++c) acc[r][c] = (f32x4){0.f, 0.f, 0.f, 0.f};

    const float* xb = x + (size_t)b * (C_ * N_);
    for (int c0 = 0; c0 < C_; c0 += 32) {
        // x tile 32cc x 64nn, float4-vectorized (4 x 256B segments / wave instr)
#pragma unroll
        for (int i = 0; i < 2; ++i) {
            int idx = t + (i << 8);            // 0..511
            int cc = idx >> 4;                 // 0..31
            int nn4 = (idx & 15) << 2;         // 0,4,..,60
            float4 xv = *(const float4*)&xb[(size_t)(c0 + cc) * N_ + n0 + nn4];
            Al[(nn4    ) * 40 + cc] = f2bs(xv.x);
            Al[(nn4 + 1) * 40 + cc] = f2bs(xv.y);
            Al[(nn4 + 2) * 40 + cc] = f2bs(xv.z);
            Al[(nn4 + 3) * 40 + cc] = f2bs(xv.w);
        }
#pragma unroll
        for (int i = 0; i < 2; ++i) {
            int idx = t + (i << 8);           // 0..511
            int d = idx >> 2, seg = idx & 3;  // 128 rows x 4 segs of 8
            *(bf16x8*)&Bl[d * 40 + seg * 8] =
                *(const bf16x8*)&WpT[d * 512 + c0 + seg * 8];
        }
        __syncthreads();
        bf16x8 af[2], bfr[4];
#pragma unroll
        for (int r = 0; r < 2; ++r)
            af[r] = *(const bf16x8*)&Al[(rowoff + 16 * r + m) * 40 + quad * 8];
#pragma unroll
        for (int c = 0; c < 4; ++c)
            bfr[c] = *(const bf16x8*)&Bl[(coloff + 16 * c + m) * 40 + quad * 8];
#pragma unroll
        for (int r = 0; r < 2; ++r)
#pragma unroll
            for (int c = 0; c < 4; ++c)
                acc[r][c] = __builtin_amdgcn_mfma_f32_16x16x32_bf16(af[r], bfr[c], acc[r][c], 0, 0, 0);
        __syncthreads();
    }
    float gv[4], bvv[4], bpv[4];
#pragma unroll
    for (int c = 0; c < 4; ++c) {
        int col = coloff + 16 * c + m;
        bpv[c] = bp[col]; gv[c] = g_in[col]; bvv[c] = b_in[col];
    }
#pragma unroll
    for (int r = 0; r < 2; ++r)
#pragma unroll
        for (int c = 0; c < 4; ++c)
#pragma unroll
            for (int g = 0; g < 4; ++g) acc[r][c][g] += bpv[c];

#pragma unroll
    for (int r = 0; r < 2; ++r) {
#pragma unroll
        for (int g = 0; g < 4; ++g) {
            float s = 0.f, s2 = 0.f;
#pragma unroll
            for (int c = 0; c < 4; ++c) { float v = acc[r][c][g]; s += v; s2 += v * v; }
#pragma unroll
            for (int off = 1; off < 16; off <<= 1) {
                s += __shfl_xor(s, off, 64);
                s2 += __shfl_xor(s2, off, 64);
            }
            if (m == 0) {
                int row = rowoff + 16 * r + quad * 4 + g;
                red[row][w & 1][0] = s;
                red[row][w & 1][1] = s2;
            }
        }
    }
    __syncthreads();
#pragma unroll
    for (int r = 0; r < 2; ++r) {
#pragma unroll
        for (int g = 0; g < 4; ++g) {
            int row = rowoff + 16 * r + quad * 4 + g;
            float s = red[row][0][0] + red[row][1][0];
            float s2 = red[row][0][1] + red[row][1][1];
            float mean = s * (1.f / 128.f);
            float var = s2 * (1.f / 128.f) - mean * mean;
            float rs = rsqrtf(var + 1e-5f);
#pragma unroll
            for (int c = 0; c < 4; ++c) {
                int col = coloff + 16 * c + m;
                float v = (acc[r][c][g] - mean) * rs * gv[c] + bvv[c];
                A2[row * 136 + col] = f2bs(v);     // LDS instead of global
            }
        }
    }
    // (A2 writes are synced by the first staging barrier of phase 2)

    // ================= phase 2: k/v MFMA (proven kv_mfma loop) =============
    const int is_v = w >> 1;
    const int rowoff2 = (w & 1) << 5;
    f32x4 acc2[2][8];
#pragma unroll
    for (int r = 0; r < 2; ++r)
#pragma unroll
        for (int c = 0; c < 8; ++c) acc2[r][c] = (f32x4){0.f, 0.f, 0.f, 0.f};

    for (int c0 = 0; c0 < D_; c0 += 32) {
#pragma unroll
        for (int i = 0; i < 2; ++i) {
            int idx = t + (i << 8);
            int d = idx >> 2, seg = idx & 3;
            *(bf16x8*)&Bl[d * 40 + seg * 8] =
                *(const bf16x8*)&WkT[d * 128 + c0 + seg * 8];
            *(bf16x8*)&Bv2[d * 40 + seg * 8] =
                *(const bf16x8*)&WvT[d * 128 + c0 + seg * 8];
        }
        __syncthreads();
        const ushort_t* Bsrc = is_v ? Bv2 : Bl;
        bf16x8 af[2], bfr[8];
#pragma unroll
        for (int r = 0; r < 2; ++r)
            af[r] = *(const bf16x8*)&A2[(rowoff2 + 16 * r + m) * 136 + c0 + quad * 8];
#pragma unroll
        for (int c = 0; c < 8; ++c)
            bfr[c] = *(const bf16x8*)&Bsrc[(16 * c + m) * 40 + quad * 8];
#pragma unroll
        for (int r = 0; r < 2; ++r)
#pragma unroll
            for (int c = 0; c < 8; ++c)
                acc2[r][c] = __builtin_amdgcn_mfma_f32_16x16x32_bf16(af[r], bfr[c], acc2[r][c], 0, 0, 0);
        __syncthreads();
    }
    const float* bias = is_v ? bv : bk;
    ushort_t* dst = is_v ? vout : kout;
    float bval[8];
#pragma unroll
    for (int c = 0; c < 8; ++c) bval[c] = bias[16 * c + m];
#pragma unroll
    for (int r = 0; r < 2; ++r) {
#pragma unroll
        for (int g = 0; g < 4; ++g) {
            int row = rowoff2 + 16 * r + quad * 4 + g;
            size_t base = ((size_t)b * N_ + n0 + row) * D_;
#pragma unroll
            for (int c = 0; c < 8; ++c)
                dst[base + 16 * c + m] = f2bs(acc2[r][c][g] + bval[c]);
        }
    }
}

// ---------------------------------------------------------------------------
// K4: attn + PV fused per n-quarter (unchanged, proven round 6).
// ---------------------------------------------------------------------------
__global__ __launch_bounds__(512, 2) void attn_pv(
    const ushort_t* __restrict__ kb, const ushort_t* __restrict__ vb,
    const float* __restrict__ qbuf,
    float* __restrict__ S_part, float* __restrict__ upd_part,
    float* __restrict__ out_attn, int last)
{
    __shared__ __align__(16) char scratch[69632];   // kvt[256][136] ush U red[64][132] f32
    __shared__ __align__(16) float at8[8][264];     // logits -> attn (quarter)
    __shared__ __align__(16) float qs[8][132];
    __shared__ float red2[4][8];
    ushort_t* kvt = (ushort_t*)scratch;
    float* red = (float*)scratch;

    const int t = threadIdx.x;
    const int qd = blockIdx.x, b = blockIdx.y;
    const int nbase = qd << 8;
    const int wv = t >> 6, lane = t & 63;
    const float SCALE = 0.08838834764831845f;

    // q: 4 KB, coalesced
    for (int i = t; i < 1024; i += 512)
        qs[i >> 7][i & 127] = qbuf[(size_t)b * 1024 + i];
    // stage k-quarter (coalesced bf16x8)
#pragma unroll
    for (int i = 0; i < 8; ++i) {
        int idx = t + (i << 9);            // 0..4095
        int rr = idx >> 4, u8 = (idx & 15) << 3;
        *(bf16x8*)&kvt[rr * 136 + u8] =
            *(const bf16x8*)&kb[((size_t)b * N_ + nbase + rr) * D_ + u8];
    }
    __syncthreads();

    // logits: thread (rr = t&255, kh = t>>8) -> 4 k-dots for its n-row
    {
        const int rr = t & 255, kh = t >> 8;
        float acc[4] = {0.f, 0.f, 0.f, 0.f};
        for (int c0 = 0; c0 < 128; c0 += 8) {
            bf16x8 kr = *(const bf16x8*)&kvt[rr * 136 + c0];
            float kf[8];
#pragma unroll
            for (int j = 0; j < 8; ++j) kf[j] = bs2f((ushort_t)kr[j]);
#pragma unroll
            for (int kk = 0; kk < 4; ++kk) {
                f32x4 qa = *(const f32x4*)&qs[4 * kh + kk][c0];
                f32x4 qb = *(const f32x4*)&qs[4 * kh + kk][c0 + 4];
                acc[kk] = fmaf(qa[0], kf[0], acc[kk]);
                acc[kk] = fmaf(qa[1], kf[1], acc[kk]);
                acc[kk] = fmaf(qa[2], kf[2], acc[kk]);
                acc[kk] = fmaf(qa[3], kf[3], acc[kk]);
                acc[kk] = fmaf(qb[0], kf[4], acc[kk]);
                acc[kk] = fmaf(qb[1], kf[5], acc[kk]);
                acc[kk] = fmaf(qb[2], kf[6], acc[kk]);
                acc[kk] = fmaf(qb[3], kf[7], acc[kk]);
            }
        }
#pragma unroll
        for (int kk = 0; kk < 4; ++kk)
            at8[4 * kh + kk][rr] = acc[kk];
    }
    __syncthreads();

    // softmax over k per local n (t<256) + per-wave S partials
    if (t < 256) {
        float l[8];
#pragma unroll
        for (int k = 0; k < 8; ++k) l[k] = at8[k][t] * SCALE;
        float mx = l[0];
#pragma unroll
        for (int k = 1; k < 8; ++k) mx = fmaxf(mx, l[k]);
        float e[8], ssum = 0.f;
#pragma unroll
        for (int k = 0; k < 8; ++k) { e[k] = expf(l[k] - mx); ssum += e[k]; }
        float inv = 1.f / ssum;
        float p[8];
#pragma unroll
        for (int k = 0; k < 8; ++k) {
            p[k] = e[k] * inv;
            at8[k][t] = p[k];
            if (last) out_attn[((size_t)b * K_ + k) * N_ + nbase + t] = p[k];
        }
#pragma unroll
        for (int k = 0; k < 8; ++k) {
            float v = p[k];
            for (int off = 32; off > 0; off >>= 1) v += __shfl_down(v, off, 64);
            if (lane == 0) red2[wv][k] = v;
        }
    }
    __syncthreads();
    if (t < 8)
        S_part[((size_t)b * 4 + qd) * 8 + t] =
            red2[0][t] + red2[1][t] + red2[2][t] + red2[3][t];

    // stage v-quarter (kvt reuse)
#pragma unroll
    for (int i = 0; i < 8; ++i) {
        int idx = t + (i << 9);
        int rr = idx >> 4, u8 = (idx & 15) << 3;
        *(bf16x8*)&kvt[rr * 136 + u8] =
            *(const bf16x8*)&vb[((size_t)b * N_ + nbase + rr) * D_ + u8];
    }
    __syncthreads();

    // PV: upd quarter-partial = attn(quarter) @ v(quarter)
    {
        float acc[8][4];
#pragma unroll
        for (int k = 0; k < 8; ++k)
#pragma unroll
            for (int j = 0; j < 4; ++j) acc[k][j] = 0.f;
        const int d4 = (t & 31) * 4, s = t >> 5;
#pragma unroll
        for (int i2 = 0; i2 < 4; ++i2) {
            const int nn = (s << 4) + (i2 << 2);
            float vf[4][4];
#pragma unroll
            for (int i = 0; i < 4; ++i) {
                ushort4 v4 = *(const ushort4*)&kvt[(nn + i) * 136 + d4];
                vf[i][0] = bs2f(v4.x); vf[i][1] = bs2f(v4.y);
                vf[i][2] = bs2f(v4.z); vf[i][3] = bs2f(v4.w);
            }
#pragma unroll
            for (int k = 0; k < 8; ++k) {
                f32x4 a4 = *(const f32x4*)&at8[k][nn];
#pragma unroll
                for (int i = 0; i < 4; ++i) {
                    acc[k][0] = fmaf(a4[i], vf[i][0], acc[k][0]);
                    acc[k][1] = fmaf(a4[i], vf[i][1], acc[k][1]);
                    acc[k][2] = fmaf(a4[i], vf[i][2], acc[k][2]);
                    acc[k][3] = fmaf(a4[i], vf[i][3], acc[k][3]);
                }
            }
        }
        __syncthreads();   // kvt reads done; scratch becomes red[]
#pragma unroll
        for (int k = 0; k < 8; ++k)
#pragma unroll
            for (int j = 0; j < 4; ++j)
                acc[k][j] += __shfl_xor(acc[k][j], 32, 64);
        if (lane < 32) {
#pragma unroll
            for (int k = 0; k < 8; ++k)
#pragma unroll
                for (int j = 0; j < 4; ++j)
                    red[(wv * 8 + k) * 132 + lane * 4 + j] = acc[k][j];
        }
        __syncthreads();
        for (int i = t; i < 1024; i += 512) {
            int k = i >> 7, d = i & 127;
            float ssum = 0.f;
#pragma unroll
            for (int w = 0; w < 8; ++w) ssum += red[(w * 8 + k) * 132 + d];
            upd_part[((size_t)b * 4 + qd) * 1024 + i] = ssum;
        }
    }
}

// ---------------------------------------------------------------------------
// K5: GRU + LN + MLP + residual + next-q (unchanged, proven round 6).
// ---------------------------------------------------------------------------
__global__ __launch_bounds__(256) void gru_mlp_q(
    const float* __restrict__ upd_part, const float* __restrict__ S_part,
    float* __restrict__ slots,
    const float* __restrict__ WTih, const float* __restrict__ WThh,
    const float* __restrict__ b_ih, const float* __restrict__ b_hh,
    const float* __restrict__ W1, const float* __restrict__ b1,
    const float* __restrict__ W2, const float* __restrict__ b2,
    const float* __restrict__ g_mlp, const float* __restrict__ b_mlp,
    const float* __restrict__ g_slots, const float* __restrict__ b_slots,
    const float* __restrict__ Wq, const float* __restrict__ bq,
    float* __restrict__ qbuf,
    float* __restrict__ out_slots, int final_iter)
{
    __shared__ float u[128], h[128], gx[384], gh[384], sn[128], tt[128], hm[256];
    __shared__ float mrs[2];
    const int t = threadIdx.x;
    const int row = blockIdx.x;           // b*8 + k
    const int b = row >> 3, k = row & 7;
    if (t < 128) {
        size_t sb = (size_t)b * 4;
        float S = S_part[(sb + 0) * 8 + k] + S_part[(sb + 1) * 8 + k]
                + S_part[(sb + 2) * 8 + k] + S_part[(sb + 3) * 8 + k];
        float inv = 1.0f / (S + 1e-8f);
        int i = k * 128 + t;
        float up = upd_part[(sb + 0) * 1024 + i] + upd_part[(sb + 1) * 1024 + i]
                 + upd_part[(sb + 2) * 1024 + i] + upd_part[(sb + 3) * 1024 + i];
        u[t] = up * inv;
        h[t] = slots[(size_t)row * D_ + t];
    }
    __syncthreads();
    {
        int j = t;
        float ax = 0.f, ah = 0.f;
        for (int c = 0; c < 128; ++c) {
            float uc = u[c], hc = h[c];
            ax = fmaf(uc, WTih[(size_t)c * 384 + j], ax);
            ah = fmaf(hc, WThh[(size_t)c * 384 + j], ah);
        }
        gx[j] = ax + b_ih[j];
        gh[j] = ah + b_hh[j];
    }
    if (t < 128) {
        int j = 256 + t;
        float ax = 0.f, ah = 0.f;
        for (int c = 0; c < 128; ++c) {
            float uc = u[c], hc = h[c];
            ax = fmaf(uc, WTih[(size_t)c * 384 + j], ax);
            ah = fmaf(hc, WThh[(size_t)c * 384 + j], ah);
        }
        gx[j] = ax + b_ih[j];
        gh[j] = ah + b_hh[j];
    }
    __syncthreads();
    if (t < 128) {
        float r = sigmoidf_(gx[t] + gh[t]);
        float z = sigmoidf_(gx[t + 128] + gh[t + 128]);
        float nv = tanhf(gx[t + 256] + r * gh[t + 256]);
        sn[t] = (1.0f - z) * nv + z * h[t];
    }
    __syncthreads();
    if (t < 64) {
        float v0 = sn[t], v1 = sn[t + 64];
        float s = v0 + v1, s2 = v0 * v0 + v1 * v1;
        for (int off = 32; off > 0; off >>= 1) {
            s += __shfl_down(s, off, 64);
            s2 += __shfl_down(s2, off, 64);
        }
        if (t == 0) {
            float mean = s * (1.f / 128.f);
            float var = s2 * (1.f / 128.f) - mean * mean;
            mrs[0] = mean; mrs[1] = rsqrtf(var + 1e-5f);
        }
    }
    __syncthreads();
    if (t < 128) tt[t] = (sn[t] - mrs[0]) * mrs[1] * g_mlp[t] + b_mlp[t];
    __syncthreads();
    {
        float a = 0.f;
        for (int c = 0; c < 128; ++c) a = fmaf(tt[c], W1[(size_t)c * 256 + t], a);
        hm[t] = gelu_exact(a + b1[t]);
    }
    __syncthreads();
    if (t < 128) {
        float a = sn[t] + b2[t];
        for (int j = 0; j < 256; ++j) a = fmaf(hm[j], W2[(size_t)j * D_ + t], a);
        slots[(size_t)row * D_ + t] = a;
        if (final_iter) out_slots[(size_t)row * D_ + t] = a;
        u[t] = a;                      // reuse u[] as new-slots buffer for q
    }
    __syncthreads();
    // ---- q for next iteration
    if (t < 64) {
        float v0 = u[t], v1 = u[t + 64];
        float s = v0 + v1, s2 = v0 * v0 + v1 * v1;
        for (int off = 32; off > 0; off >>= 1) {
            s += __shfl_down(s, off, 64);
            s2 += __shfl_down(s2, off, 64);
        }
        if (t == 0) {
            float mean = s * (1.f / 128.f);
            float var = s2 * (1.f / 128.f) - mean * mean;
            mrs[0] = mean; mrs[1] = rsqrtf(var + 1e-5f);
        }
    }
    __syncthreads();
    if (t < 128) tt[t] = (u[t] - mrs[0]) * mrs[1] * g_slots[t] + b_slots[t];
    __syncthreads();
    if (!final_iter && t < 128) {
        float a = bq[t];
        for (int c = 0; c < 128; ++c) a = fmaf(tt[c], Wq[(size_t)c * D_ + t], a);
        qbuf[(size_t)row * D_ + t] = a;
    }
}

// ---------------------------------------------------------------------------
extern "C" void kernel_launch(void* const* d_in, const int* in_sizes, int n_in,
                              void* d_out, int out_size, void* d_ws, size_t ws_size,
                              hipStream_t stream) {
    const float* x       = (const float*)d_in[0];
    const float* noise   = (const float*)d_in[1];
    const float* slot_mu = (const float*)d_in[2];
    const float* slot_ls = (const float*)d_in[3];
    const float* Wp      = (const float*)d_in[4];
    const float* bp      = (const float*)d_in[5];
    const float* g_in    = (const float*)d_in[6];
    const float* b_in    = (const float*)d_in[7];
    const float* Wq      = (const float*)d_in[8];
    const float* bq      = (const float*)d_in[9];
    const float* Wk      = (const float*)d_in[10];
    const float* bk      = (const float*)d_in[11];
    const float* Wv      = (const float*)d_in[12];
    const float* bv      = (const float*)d_in[13];
    const float* W_ih    = (const float*)d_in[14];
    const float* W_hh    = (const float*)d_in[15];
    const float* b_ih    = (const float*)d_in[16];
    const float* b_hh    = (const float*)d_in[17];
    const float* W1      = (const float*)d_in[18];
    const float* b1      = (const float*)d_in[19];
    const float* W2      = (const float*)d_in[20];
    const float* b2      = (const float*)d_in[21];
    const float* g_slots = (const float*)d_in[22];
    const float* b_slots = (const float*)d_in[23];
    const float* g_mlp   = (const float*)d_in[24];
    const float* b_mlp   = (const float*)d_in[25];

    float* out_slots = (float*)d_out;            // [64,8,128] fp32
    float* out_attn  = (float*)d_out + 65536;    // [64,8,1024] fp32

    // workspace layout (float units) — offsets unchanged; inputsb now unused
    float* wsf = (float*)d_ws;
    ushort_t* kb = (ushort_t*)(wsf + 4194304);             // 65536x128 bf16
    ushort_t* vb = (ushort_t*)(wsf + 8388608);             // 65536x128 bf16
    float* slots    = wsf + 12582912;   // 512*128
    float* qbuf     = wsf + 12648448;   // 512*128
    float* upd_part = wsf + 12713984;   // [64][4][8][128] = 262144
    float* S_part   = wsf + 12976128;   // [64][4][8] = 2048
    ushort_t* WpT = (ushort_t*)(wsf + 13304320);  // 128x512 bf16
    ushort_t* WkT = (ushort_t*)(wsf + 13337088);  // 128x128 bf16
    ushort_t* WvT = (ushort_t*)(wsf + 13345280);  // 128x128 bf16
    float* WTih = wsf + 13353472;    // 128x384 fp32
    float* WThh = wsf + 13402624;    // 128x384 fp32

    prep_init<<<dim3(512), dim3(256), 0, stream>>>(
        Wp, Wk, Wv, W_ih, W_hh, noise, slot_mu, slot_ls,
        g_slots, b_slots, Wq, bq,
        WpT, WkT, WvT, WTih, WThh, slots, qbuf);
    proj_kv<<<dim3(1024), dim3(256), 0, stream>>>(
        x, WpT, bp, g_in, b_in, WkT, bk, WvT, bv, kb, vb);

    for (int it = 0; it < 3; ++it) {
        int last = (it == 2) ? 1 : 0;
        attn_pv<<<dim3(4, 64), dim3(512), 0, stream>>>(
            kb, vb, qbuf, S_part, upd_part, out_attn, last);
        gru_mlp_q<<<dim3(512), dim3(256), 0, stream>>>(
            upd_part, S_part, slots, WTih, WThh, b_ih, b_hh,
            W1, b1, W2, b2, g_mlp, b_mlp, g_slots, b_slots,
            Wq, bq, qbuf, out_slots, last);
    }
}